// Round 1
// baseline (184.977 us; speedup 1.0000x reference)
//
#include <hip/hip_runtime.h>

#define QMAX 127.0f

typedef int v4i __attribute__((ext_vector_type(4)));

__device__ __forceinline__ void gload_lds16(const void* g, void* l) {
  __builtin_amdgcn_global_load_lds(
      (const __attribute__((address_space(1))) void*)g,
      (__attribute__((address_space(3))) void*)l, 16, 0, 0);
}

// ---------------- quantize x: f32 -> int8 ----------------
__global__ void quant_x_kernel(const float* __restrict__ x,
                               signed char* __restrict__ q,
                               const float* __restrict__ pAin, int n4) {
  int t = blockIdx.x * blockDim.x + threadIdx.x;
  if (t >= n4) return;
  float s = QMAX / pAin[0];
  float4 v = reinterpret_cast<const float4*>(x)[t];
  int q0 = (int)fminf(fmaxf(rintf(v.x * s), -QMAX), QMAX);
  int q1 = (int)fminf(fmaxf(rintf(v.y * s), -QMAX), QMAX);
  int q2 = (int)fminf(fmaxf(rintf(v.z * s), -QMAX), QMAX);
  int q3 = (int)fminf(fmaxf(rintf(v.w * s), -QMAX), QMAX);
  unsigned packed = (unsigned)(q0 & 0xff) | ((unsigned)(q1 & 0xff) << 8) |
                    ((unsigned)(q2 & 0xff) << 16) | ((unsigned)(q3 & 0xff) << 24);
  reinterpret_cast<unsigned*>(q)[t] = packed;
}

// ---------------- pack W: int32 [N][K+1] -> int8 [N][K] + bias[N] ----------------
// Kq = K/4 = 1<<kshift
__global__ void pack_w_kernel(const int* __restrict__ W,
                              signed char* __restrict__ W8,
                              int* __restrict__ bias,
                              unsigned total, int kshift) {
  unsigned t = blockIdx.x * blockDim.x + threadIdx.x;
  if (t >= total) return;
  unsigned row = t >> kshift;
  unsigned j = t & ((1u << kshift) - 1u);
  unsigned K = 4u << kshift;
  size_t srcBase = (size_t)row * (size_t)(K + 1) + (size_t)j * 4;
  int b0 = W[srcBase + 0], b1 = W[srcBase + 1], b2 = W[srcBase + 2], b3 = W[srcBase + 3];
  unsigned packed = (unsigned)(b0 & 0xff) | ((unsigned)(b1 & 0xff) << 8) |
                    ((unsigned)(b2 & 0xff) << 16) | ((unsigned)(b3 & 0xff) << 24);
  reinterpret_cast<unsigned*>(W8)[t] = packed;
  if (j == 0) bias[row] = W[(size_t)row * (K + 1) + K];
}

// ---------------- fused int8 GEMM ----------------
// out[b][n] = epilogue( sum_k A[b][k]*Bw[n][k] + bias[n] )
// MODE 0: dequant -> relu -> requant int8 (next layer's A)
// MODE 1: dequant -> f32 out
template <int MODE>
__global__ __launch_bounds__(256)
void qgemm_kernel(const signed char* __restrict__ A,
                  const signed char* __restrict__ Bw,
                  const int* __restrict__ bias,
                  void* __restrict__ outp,
                  int N, int K, int nbn,
                  const float* __restrict__ pAin,
                  const float* __restrict__ pAw,
                  const float* __restrict__ pAnext) {
  __shared__ signed char lds[32768];
  signed char* ldsA = lds;
  signed char* ldsB = lds + 16384;

  // bijective XCD swizzle (all launches have gridDim.x % 8 == 0)
  int nwg = gridDim.x;
  int bid = blockIdx.x;
  int per = nwg >> 3;
  int swz = (bid & 7) * per + (bid >> 3);
  int brow = swz / nbn;
  int bcol = swz - brow * nbn;
  int browBase = brow << 7;
  int bcolBase = bcol << 7;

  int tid = threadIdx.x;
  int lane = tid & 63;
  int l15 = lane & 15;
  int hi = lane >> 4;
  int wid = tid >> 6;
  int wr = (wid >> 1) << 6;   // wave row offset within 128-tile
  int wc = (wid & 1) << 6;    // wave col offset

  v4i acc[4][4] = {};

  int nk = K >> 7;            // BK = 128 bytes of K per step
  for (int kt = 0; kt < nk; ++kt) {
    int k0 = kt << 7;
    // -------- stage A,B tiles (128 rows x 128 B each) via global_load_lds --------
    // LDS dest is linear (wave-uniform base + lane*16); swizzle is applied by
    // pre-swizzling the per-lane GLOBAL source (rule #21: both-sides involution).
#pragma unroll
    for (int i = 0; i < 4; ++i) {
      int c = i * 256 + tid;          // 16B chunk index, 8 chunks per row
      int r = c >> 3;
      int osrc = ((c & 7) << 4) ^ ((r & 7) << 4);
      gload_lds16(A + (size_t)(browBase + r) * K + (k0 + osrc), ldsA + c * 16);
      gload_lds16(Bw + (size_t)(bcolBase + r) * K + (k0 + osrc), ldsB + c * 16);
    }
    __syncthreads();   // drains vmcnt before barrier -> staged data visible
    // -------- compute: 2 k-halves x 4x4 fragments of 16x16x64 i8 MFMA --------
#pragma unroll
    for (int kk = 0; kk < 2; ++kk) {
      v4i a[4], b[4];
#pragma unroll
      for (int m = 0; m < 4; ++m) {
        int row = wr + m * 16 + l15;
        int off = (kk * 64 + hi * 16) ^ ((row & 7) << 4);
        a[m] = *reinterpret_cast<const v4i*>(ldsA + row * 128 + off);
      }
#pragma unroll
      for (int n = 0; n < 4; ++n) {
        int row = wc + n * 16 + l15;
        int off = (kk * 64 + hi * 16) ^ ((row & 7) << 4);
        b[n] = *reinterpret_cast<const v4i*>(ldsB + row * 128 + off);
      }
#pragma unroll
      for (int m = 0; m < 4; ++m)
#pragma unroll
        for (int n = 0; n < 4; ++n)
          acc[m][n] = __builtin_amdgcn_mfma_i32_16x16x64_i8(a[m], b[n], acc[m][n], 0, 0, 0);
    }
    __syncthreads();   // all waves done reading before next tile overwrites LDS
  }

  // -------- epilogue: bias add (int, exact), dequant (f32, reference op order) --------
  // reference: acc_f32 * (a_w * a_in / (127*127)); keep the division for bit-exactness
  float sDeq = (pAw[0] * pAin[0]) / (QMAX * QMAX);

  if (MODE == 0) {
    float sQ = QMAX / pAnext[0];
    signed char* O = reinterpret_cast<signed char*>(outp);
#pragma unroll
    for (int n = 0; n < 4; ++n) {
      int gcol = bcolBase + wc + n * 16 + l15;
      int bv = bias[gcol];
#pragma unroll
      for (int m = 0; m < 4; ++m) {
        int growb = browBase + wr + m * 16 + (hi << 2);
#pragma unroll
        for (int r = 0; r < 4; ++r) {
          float f = (float)(acc[m][n][r] + bv) * sDeq;
          f = fmaxf(f, 0.0f);                       // relu
          float qf = fminf(fmaxf(rintf(f * sQ), -QMAX), QMAX);
          O[(size_t)(growb + r) * N + gcol] = (signed char)(int)qf;
        }
      }
    }
  } else {
    float* O = reinterpret_cast<float*>(outp);
#pragma unroll
    for (int n = 0; n < 4; ++n) {
      int gcol = bcolBase + wc + n * 16 + l15;
      int bv = bias[gcol];
#pragma unroll
      for (int m = 0; m < 4; ++m) {
        int growb = browBase + wr + m * 16 + (hi << 2);
#pragma unroll
        for (int r = 0; r < 4; ++r) {
          O[(size_t)(growb + r) * N + gcol] = (float)(acc[m][n][r] + bv) * sDeq;
        }
      }
    }
  }
}

extern "C" void kernel_launch(void* const* d_in, const int* in_sizes, int n_in,
                              void* d_out, int out_size, void* d_ws, size_t ws_size,
                              hipStream_t stream) {
  const float* x     = (const float*)d_in[0];
  const float* a_in0 = (const float*)d_in[1];
  const float* a_w0  = (const float*)d_in[2];
  const float* a_in2 = (const float*)d_in[3];
  const float* a_w2  = (const float*)d_in[4];
  const float* a_in4 = (const float*)d_in[5];
  const float* a_w4  = (const float*)d_in[6];
  const int*   W0    = (const int*)d_in[7];
  const int*   W1    = (const int*)d_in[8];
  const int*   W2    = (const int*)d_in[9];
  float* out = (float*)d_out;

  constexpr int B = 4096, IN = 1024, H0 = 4096, H1 = 4096, OUTN = 1024;

  char* ws = (char*)d_ws;
  size_t off = 0;
  auto alloc = [&](size_t sz) {
    char* p = ws + off;
    off += (sz + 255) & ~(size_t)255;
    return p;
  };
  signed char* qa0 = (signed char*)alloc((size_t)B * IN);    // 4 MiB
  signed char* qa1 = (signed char*)alloc((size_t)B * H0);    // 16 MiB
  signed char* qa2 = (signed char*)alloc((size_t)B * H1);    // 16 MiB
  signed char* W0p = (signed char*)alloc((size_t)H0 * IN);   // 4 MiB
  signed char* W1p = (signed char*)alloc((size_t)H1 * H0);   // 16 MiB
  signed char* W2p = (signed char*)alloc((size_t)OUTN * H1); // 4 MiB
  int* b0 = (int*)alloc((size_t)H0 * 4);
  int* b1 = (int*)alloc((size_t)H1 * 4);
  int* b2 = (int*)alloc((size_t)OUTN * 4);

  // pack weights (int32 -> int8, extract bias column)
  {
    unsigned total0 = (unsigned)H0 * (IN / 4);   // kshift 8
    pack_w_kernel<<<(total0 + 255) / 256, 256, 0, stream>>>(W0, W0p, b0, total0, 8);
    unsigned total1 = (unsigned)H1 * (H0 / 4);   // kshift 10
    pack_w_kernel<<<(total1 + 255) / 256, 256, 0, stream>>>(W1, W1p, b1, total1, 10);
    unsigned total2 = (unsigned)OUTN * (H1 / 4); // kshift 10
    pack_w_kernel<<<(total2 + 255) / 256, 256, 0, stream>>>(W2, W2p, b2, total2, 10);
  }

  // quantize x
  {
    int n4 = B * IN / 4;
    quant_x_kernel<<<(n4 + 255) / 256, 256, 0, stream>>>(x, qa0, a_in0, n4);
  }

  // layer 0: [B,IN] x [H0,IN]^T -> qa1 (int8, relu+requant with a_in2)
  qgemm_kernel<0><<<(B / 128) * (H0 / 128), 256, 0, stream>>>(
      qa0, W0p, b0, qa1, H0, IN, H0 / 128, a_in0, a_w0, a_in2);

  // layer 1: [B,H0] x [H1,H0]^T -> qa2 (int8, relu+requant with a_in4)
  qgemm_kernel<0><<<(B / 128) * (H1 / 128), 256, 0, stream>>>(
      qa1, W1p, b1, qa2, H1, H0, H1 / 128, a_in2, a_w2, a_in4);

  // layer 2: [B,H1] x [OUT,H1]^T -> f32 out
  qgemm_kernel<1><<<(B / 128) * (OUTN / 128), 256, 0, stream>>>(
      qa2, W2p, b2, out, OUTN, H1, OUTN / 128, a_in4, a_w4, a_in4);
}

// Round 2
// 148.309 us; speedup vs baseline: 1.2472x; 1.2472x over previous
//
#include <hip/hip_runtime.h>

#define QMAX 127.0f

typedef int v4i __attribute__((ext_vector_type(4)));

__device__ __forceinline__ void gload_lds16(const void* g, void* l) {
  __builtin_amdgcn_global_load_lds(
      (const __attribute__((address_space(1))) void*)g,
      (__attribute__((address_space(3))) void*)l, 16, 0, 0);
}

// ---------------- quantize x: f32 -> int8 ----------------
__global__ void quant_x_kernel(const float* __restrict__ x,
                               signed char* __restrict__ q,
                               const float* __restrict__ pAin, int n4) {
  int t = blockIdx.x * blockDim.x + threadIdx.x;
  if (t >= n4) return;
  float s = QMAX / pAin[0];
  float4 v = reinterpret_cast<const float4*>(x)[t];
  int q0 = (int)fminf(fmaxf(rintf(v.x * s), -QMAX), QMAX);
  int q1 = (int)fminf(fmaxf(rintf(v.y * s), -QMAX), QMAX);
  int q2 = (int)fminf(fmaxf(rintf(v.z * s), -QMAX), QMAX);
  int q3 = (int)fminf(fmaxf(rintf(v.w * s), -QMAX), QMAX);
  unsigned packed = (unsigned)(q0 & 0xff) | ((unsigned)(q1 & 0xff) << 8) |
                    ((unsigned)(q2 & 0xff) << 16) | ((unsigned)(q3 & 0xff) << 24);
  reinterpret_cast<unsigned*>(q)[t] = packed;
}

// ---------------- pack W: int32 [N][K+1] -> int8 [N][K] + bias[N] ----------------
__global__ void pack_w_kernel(const int* __restrict__ W,
                              signed char* __restrict__ W8,
                              int* __restrict__ bias,
                              unsigned total, int kshift) {
  unsigned t = blockIdx.x * blockDim.x + threadIdx.x;
  if (t >= total) return;
  unsigned row = t >> kshift;
  unsigned j = t & ((1u << kshift) - 1u);
  unsigned K = 4u << kshift;
  size_t srcBase = (size_t)row * (size_t)(K + 1) + (size_t)j * 4;
  int b0 = W[srcBase + 0], b1 = W[srcBase + 1], b2 = W[srcBase + 2], b3 = W[srcBase + 3];
  unsigned packed = (unsigned)(b0 & 0xff) | ((unsigned)(b1 & 0xff) << 8) |
                    ((unsigned)(b2 & 0xff) << 16) | ((unsigned)(b3 & 0xff) << 24);
  reinterpret_cast<unsigned*>(W8)[t] = packed;
  if (j == 0) bias[row] = W[(size_t)row * (K + 1) + K];
}

// =====================================================================
// 256x256-tile 8-phase int8 GEMM (T2+T3+T4+T5), MODE-0 epilogue only:
// dequant -> relu -> requant int8.
// 8 waves (2M x 4N), per-wave output 128x64, BK=128 bytes, LDS 128 KiB
// (2 dbuf x [A 32K | B 32K]).  vmcnt(6) only at phases 4/8 (3 half-tiles
// = 6 loads in flight).  Stage-at-phase-p only touches regions whose
// last ds_read was phase <= p-1 (race-free by construction).
// =====================================================================

#define FENCE() asm volatile("" ::: "memory")
#define BARRIER()                      \
  do {                                 \
    FENCE();                           \
    __builtin_amdgcn_s_barrier();      \
    FENCE();                           \
  } while (0)
#define LGK0() asm volatile("s_waitcnt lgkmcnt(0)" ::: "memory")
#define VMC6() asm volatile("s_waitcnt vmcnt(6)" ::: "memory")
#define VMC0() asm volatile("s_waitcnt vmcnt(0)" ::: "memory")

#define STAGE_A(bf, h, t)                                                     \
  do {                                                                        \
    const signed char* _g = gA + (size_t)((h) * 128) * K + (size_t)(t) * 128; \
    signed char* _l = ldsA + (bf) * 32768 + (h) * 16384 + ldsThr;             \
    gload_lds16(_g, _l);                                                      \
    gload_lds16(_g + (size_t)8 * K, _l + 1024);                               \
  } while (0)

#define STAGE_B(bf, h, t)                                                     \
  do {                                                                        \
    const signed char* _g = gB + (size_t)((h) * 128) * K + (size_t)(t) * 128; \
    signed char* _l = ldsB + (bf) * 32768 + (h) * 16384 + ldsThr;             \
    gload_lds16(_g, _l);                                                      \
    gload_lds16(_g + (size_t)8 * K, _l + 1024);                               \
  } while (0)

#define LDA(bf, qm)                                                           \
  do {                                                                        \
    _Pragma("unroll") for (int m = 0; m < 4; ++m) {                           \
      int row = wm * 128 + (qm) * 64 + m * 16 + l15;                          \
      _Pragma("unroll") for (int kk = 0; kk < 2; ++kk) {                      \
        int off = (kk * 64 + hi * 16) ^ ((row & 7) << 4);                     \
        aR[m][kk] = *(const v4i*)(ldsA + (bf) * 32768 + row * 128 + off);     \
      }                                                                       \
    }                                                                         \
  } while (0)

#define LDB(bf)                                                               \
  do {                                                                        \
    _Pragma("unroll") for (int n = 0; n < 4; ++n) {                           \
      int row = wn * 64 + n * 16 + l15;                                       \
      _Pragma("unroll") for (int kk = 0; kk < 2; ++kk) {                      \
        int off = (kk * 64 + hi * 16) ^ ((row & 7) << 4);                     \
        bR[n][kk] = *(const v4i*)(ldsB + (bf) * 32768 + row * 128 + off);     \
      }                                                                       \
    }                                                                         \
  } while (0)

#define MFMAQ(qm, qn)                                                         \
  do {                                                                        \
    __builtin_amdgcn_s_setprio(1);                                            \
    _Pragma("unroll") for (int m = 0; m < 4; ++m)                             \
    _Pragma("unroll") for (int n = 0; n < 2; ++n)                             \
    _Pragma("unroll") for (int kk = 0; kk < 2; ++kk)                          \
      acc[(qm) * 4 + m][(qn) * 2 + n] = __builtin_amdgcn_mfma_i32_16x16x64_i8(\
          aR[m][kk], bR[(qn) * 2 + n][kk], acc[(qm) * 4 + m][(qn) * 2 + n],   \
          0, 0, 0);                                                           \
    __builtin_amdgcn_s_setprio(0);                                            \
  } while (0)

__global__ __launch_bounds__(512, 2)
void qgemm256_kernel(const signed char* __restrict__ A,
                     const signed char* __restrict__ Bw,
                     const int* __restrict__ bias,
                     signed char* __restrict__ O,
                     int N, int K, int nbn,
                     const float* __restrict__ pAin,
                     const float* __restrict__ pAw,
                     const float* __restrict__ pAnext) {
  extern __shared__ signed char lds[];
  signed char* ldsA = lds;           // [0,64K): buf0 [0,32K), buf1 [32K,64K)
  signed char* ldsB = lds + 65536;   // [64K,128K)

  const int nwg = gridDim.x, bid = blockIdx.x, per = nwg >> 3;
  const int swz = (bid & 7) * per + (bid >> 3);
  const int brow = swz / nbn, bcol = swz - brow * nbn;
  const int browBase = brow << 8, bcolBase = bcol << 8;

  const int tid = threadIdx.x;
  const int lane = tid & 63, l15 = lane & 15, hi = lane >> 4;
  const int wid = tid >> 6, wm = wid >> 2, wn = wid & 3;

  // staging thread-constants: j=0 row within half, source chunk (involution)
  const int rloc = (wid << 4) + (lane >> 3);
  const int csrc = (lane & 7) ^ ((lane >> 3) & 7);
  const signed char* gA = A + (size_t)(browBase + rloc) * K + csrc * 16;
  const signed char* gB = Bw + (size_t)(bcolBase + rloc) * K + csrc * 16;
  const int ldsThr = (wid << 11) + lane * 16;

  v4i acc[8][4] = {};
  v4i aR[4][2], bR[4][2];

  const int nk = K >> 7, niter = nk >> 1, nkm = nk - 1;

  // prologue: tile0 {B0,B1,A0,A1}, tile1 {B0,B1,A0}; leave tile1's 3 halves
  // (6 loads) in flight.
  STAGE_B(0, 0, 0); STAGE_B(0, 1, 0); STAGE_A(0, 0, 0); STAGE_A(0, 1, 0);
  STAGE_B(1, 0, 1); STAGE_B(1, 1, 1); STAGE_A(1, 0, 1);
  VMC6();
  BARRIER();

#pragma unroll 1
  for (int i = 0; i < niter; ++i) {
    const int t1 = 2 * i + 1;
    const int tE = (2 * i + 2) & nkm;   // wrapped: always issue (exact vmcnt)
    const int tO = (2 * i + 3) & nkm;
    // ph1: reads buf0 A-qm0 + B-all; stage odd-tile A1 (buf1.A last read ph7-prev)
    LDA(0, 0); LDB(0);
    STAGE_A(1, 1, t1);
    BARRIER(); LGK0();
    MFMAQ(0, 0);
    BARRIER();
    // ph2: stage tE.B0 (buf0.B last read ph1)
    STAGE_B(0, 0, tE);
    BARRIER();
    MFMAQ(0, 1);
    BARRIER();
    // ph3: reads buf0 A-qm1; stage tE.B1
    LDA(0, 1);
    STAGE_B(0, 1, tE);
    BARRIER(); LGK0();
    MFMAQ(1, 0);
    BARRIER();
    // ph4: stage tE.A0 (buf0.A last read ph3); counted wait covers odd tile
    STAGE_A(0, 0, tE);
    VMC6();
    BARRIER();
    MFMAQ(1, 1);
    BARRIER();
    // ph5: reads buf1 A-qm0 + B-all; stage tE.A1
    LDA(1, 0); LDB(1);
    STAGE_A(0, 1, tE);
    BARRIER(); LGK0();
    MFMAQ(0, 0);
    BARRIER();
    // ph6: stage tO.B0 (buf1.B last read ph5)
    STAGE_B(1, 0, tO);
    BARRIER();
    MFMAQ(0, 1);
    BARRIER();
    // ph7: reads buf1 A-qm1; stage tO.B1
    LDA(1, 1);
    STAGE_B(1, 1, tO);
    BARRIER(); LGK0();
    MFMAQ(1, 0);
    BARRIER();
    // ph8: stage tO.A0 (buf1.A last read ph7); counted wait covers even tile
    STAGE_A(1, 0, tO);
    VMC6();
    BARRIER();
    MFMAQ(1, 1);
    BARRIER();
  }

  VMC0();  // drain orphan prefetches before LDS dealloc / epilogue

  const float sDeq = (pAw[0] * pAin[0]) / (QMAX * QMAX);
  const float sQ = QMAX / pAnext[0];
#pragma unroll
  for (int nf = 0; nf < 4; ++nf) {
    const int gcol = bcolBase + wn * 64 + nf * 16 + l15;
    const int bv = bias[gcol];
#pragma unroll
    for (int mf = 0; mf < 8; ++mf) {
      const int gr = browBase + wm * 128 + mf * 16 + (hi << 2);
#pragma unroll
      for (int r = 0; r < 4; ++r) {
        float f = (float)(acc[mf][nf][r] + bv) * sDeq;
        f = fmaxf(f, 0.0f);
        float qf = fminf(fmaxf(rintf(f * sQ), -QMAX), QMAX);
        O[(size_t)(gr + r) * N + gcol] = (signed char)(int)qf;
      }
    }
  }
}

// ---------------- 128x128-tile 2-barrier int8 GEMM (layer 2, f32 out) -------
template <int MODE>
__global__ __launch_bounds__(256)
void qgemm_kernel(const signed char* __restrict__ A,
                  const signed char* __restrict__ Bw,
                  const int* __restrict__ bias,
                  void* __restrict__ outp,
                  int N, int K, int nbn,
                  const float* __restrict__ pAin,
                  const float* __restrict__ pAw,
                  const float* __restrict__ pAnext) {
  __shared__ signed char slds[32768];
  signed char* ldsA = slds;
  signed char* ldsB = slds + 16384;

  int nwg = gridDim.x;
  int bid = blockIdx.x;
  int per = nwg >> 3;
  int swz = (bid & 7) * per + (bid >> 3);
  int brow = swz / nbn;
  int bcol = swz - brow * nbn;
  int browBase = brow << 7;
  int bcolBase = bcol << 7;

  int tid = threadIdx.x;
  int lane = tid & 63;
  int l15 = lane & 15;
  int hi = lane >> 4;
  int wid = tid >> 6;
  int wr = (wid >> 1) << 6;
  int wc = (wid & 1) << 6;

  v4i acc[4][4] = {};

  int nk = K >> 7;
  for (int kt = 0; kt < nk; ++kt) {
    int k0 = kt << 7;
#pragma unroll
    for (int i = 0; i < 4; ++i) {
      int c = i * 256 + tid;
      int r = c >> 3;
      int osrc = ((c & 7) << 4) ^ ((r & 7) << 4);
      gload_lds16(A + (size_t)(browBase + r) * K + (k0 + osrc), ldsA + c * 16);
      gload_lds16(Bw + (size_t)(bcolBase + r) * K + (k0 + osrc), ldsB + c * 16);
    }
    __syncthreads();
#pragma unroll
    for (int kk = 0; kk < 2; ++kk) {
      v4i a[4], b[4];
#pragma unroll
      for (int m = 0; m < 4; ++m) {
        int row = wr + m * 16 + l15;
        int off = (kk * 64 + hi * 16) ^ ((row & 7) << 4);
        a[m] = *reinterpret_cast<const v4i*>(ldsA + row * 128 + off);
      }
#pragma unroll
      for (int n = 0; n < 4; ++n) {
        int row = wc + n * 16 + l15;
        int off = (kk * 64 + hi * 16) ^ ((row & 7) << 4);
        b[n] = *reinterpret_cast<const v4i*>(ldsB + row * 128 + off);
      }
#pragma unroll
      for (int m = 0; m < 4; ++m)
#pragma unroll
        for (int n = 0; n < 4; ++n)
          acc[m][n] = __builtin_amdgcn_mfma_i32_16x16x64_i8(a[m], b[n], acc[m][n], 0, 0, 0);
    }
    __syncthreads();
  }

  float sDeq = (pAw[0] * pAin[0]) / (QMAX * QMAX);

  if (MODE == 0) {
    float sQ = QMAX / pAnext[0];
    signed char* O = reinterpret_cast<signed char*>(outp);
#pragma unroll
    for (int n = 0; n < 4; ++n) {
      int gcol = bcolBase + wc + n * 16 + l15;
      int bv = bias[gcol];
#pragma unroll
      for (int m = 0; m < 4; ++m) {
        int growb = browBase + wr + m * 16 + (hi << 2);
#pragma unroll
        for (int r = 0; r < 4; ++r) {
          float f = (float)(acc[m][n][r] + bv) * sDeq;
          f = fmaxf(f, 0.0f);
          float qf = fminf(fmaxf(rintf(f * sQ), -QMAX), QMAX);
          O[(size_t)(growb + r) * N + gcol] = (signed char)(int)qf;
        }
      }
    }
  } else {
    float* O = reinterpret_cast<float*>(outp);
#pragma unroll
    for (int n = 0; n < 4; ++n) {
      int gcol = bcolBase + wc + n * 16 + l15;
      int bv = bias[gcol];
#pragma unroll
      for (int m = 0; m < 4; ++m) {
        int growb = browBase + wr + m * 16 + (hi << 2);
#pragma unroll
        for (int r = 0; r < 4; ++r) {
          O[(size_t)(growb + r) * N + gcol] = (float)(acc[m][n][r] + bv) * sDeq;
        }
      }
    }
  }
}

extern "C" void kernel_launch(void* const* d_in, const int* in_sizes, int n_in,
                              void* d_out, int out_size, void* d_ws, size_t ws_size,
                              hipStream_t stream) {
  const float* x     = (const float*)d_in[0];
  const float* a_in0 = (const float*)d_in[1];
  const float* a_w0  = (const float*)d_in[2];
  const float* a_in2 = (const float*)d_in[3];
  const float* a_w2  = (const float*)d_in[4];
  const float* a_in4 = (const float*)d_in[5];
  const float* a_w4  = (const float*)d_in[6];
  const int*   W0    = (const int*)d_in[7];
  const int*   W1    = (const int*)d_in[8];
  const int*   W2    = (const int*)d_in[9];
  float* out = (float*)d_out;

  constexpr int B = 4096, IN = 1024, H0 = 4096, H1 = 4096, OUTN = 1024;

  char* ws = (char*)d_ws;
  size_t off = 0;
  auto alloc = [&](size_t sz) {
    char* p = ws + off;
    off += (sz + 255) & ~(size_t)255;
    return p;
  };
  signed char* qa0 = (signed char*)alloc((size_t)B * IN);
  signed char* qa1 = (signed char*)alloc((size_t)B * H0);
  signed char* qa2 = (signed char*)alloc((size_t)B * H1);
  signed char* W0p = (signed char*)alloc((size_t)H0 * IN);
  signed char* W1p = (signed char*)alloc((size_t)H1 * H0);
  signed char* W2p = (signed char*)alloc((size_t)OUTN * H1);
  int* b0 = (int*)alloc((size_t)H0 * 4);
  int* b1 = (int*)alloc((size_t)H1 * 4);
  int* b2 = (int*)alloc((size_t)OUTN * 4);

  // allow 128 KiB dynamic LDS for the 8-phase kernel (idempotent, host-side)
  hipFuncSetAttribute((const void*)qgemm256_kernel,
                      hipFuncAttributeMaxDynamicSharedMemorySize, 131072);

  // pack weights
  {
    unsigned total0 = (unsigned)H0 * (IN / 4);
    pack_w_kernel<<<(total0 + 255) / 256, 256, 0, stream>>>(W0, W0p, b0, total0, 8);
    unsigned total1 = (unsigned)H1 * (H0 / 4);
    pack_w_kernel<<<(total1 + 255) / 256, 256, 0, stream>>>(W1, W1p, b1, total1, 10);
    unsigned total2 = (unsigned)OUTN * (H1 / 4);
    pack_w_kernel<<<(total2 + 255) / 256, 256, 0, stream>>>(W2, W2p, b2, total2, 10);
  }

  // quantize x
  {
    int n4 = B * IN / 4;
    quant_x_kernel<<<(n4 + 255) / 256, 256, 0, stream>>>(x, qa0, a_in0, n4);
  }

  // layer 0: [B,IN]x[H0,IN]^T -> qa1 (int8), 256^2 8-phase, grid 16x16=256
  qgemm256_kernel<<<(B / 256) * (H0 / 256), 512, 131072, stream>>>(
      qa0, W0p, b0, qa1, H0, IN, H0 / 256, a_in0, a_w0, a_in2);

  // layer 1: [B,H0]x[H1,H0]^T -> qa2 (int8), 256^2 8-phase, grid 16x16=256
  qgemm256_kernel<<<(B / 256) * (H1 / 256), 512, 131072, stream>>>(
      qa1, W1p, b1, qa2, H1, H0, H1 / 256, a_in2, a_w2, a_in4);

  // layer 2: [B,H1]x[OUT,H1]^T -> f32 out, 128^2 kernel, grid 32x8=256
  qgemm_kernel<1><<<(B / 128) * (OUTN / 128), 256, 0, stream>>>(
      qa2, W2p, b2, out, OUTN, H1, OUTN / 128, a_in4, a_w4, a_in4);
}

// Round 3
// 141.531 us; speedup vs baseline: 1.3070x; 1.0479x over previous
//
#include <hip/hip_runtime.h>

#define QMAX 127.0f

typedef int v4i __attribute__((ext_vector_type(4)));

__device__ __forceinline__ void gload_lds16(const void* g, void* l) {
  __builtin_amdgcn_global_load_lds(
      (const __attribute__((address_space(1))) void*)g,
      (__attribute__((address_space(3))) void*)l, 16, 0, 0);
}

// ---------------- merged prep: pack W0/W1/W2 + quantize x (1 launch) --------
__device__ __forceinline__ void pack_body(const int* __restrict__ W,
                                          signed char* __restrict__ W8,
                                          int* __restrict__ bias,
                                          unsigned lblk, int kshift) {
  unsigned t = lblk * 256u + threadIdx.x;
  unsigned row = t >> kshift;
  unsigned j = t & ((1u << kshift) - 1u);
  unsigned K = 4u << kshift;
  size_t srcBase = (size_t)row * (size_t)(K + 1) + (size_t)j * 4;
  int c0 = W[srcBase + 0], c1 = W[srcBase + 1], c2 = W[srcBase + 2], c3 = W[srcBase + 3];
  unsigned packed = (unsigned)(c0 & 0xff) | ((unsigned)(c1 & 0xff) << 8) |
                    ((unsigned)(c2 & 0xff) << 16) | ((unsigned)(c3 & 0xff) << 24);
  reinterpret_cast<unsigned*>(W8)[t] = packed;
  if (j == 0) bias[row] = W[(size_t)row * (K + 1) + K];
}

__global__ void prep_kernel(const float* __restrict__ x,
                            signed char* __restrict__ qa0,
                            const float* __restrict__ pAin,
                            const int* __restrict__ W0, signed char* __restrict__ W0p, int* __restrict__ b0,
                            const int* __restrict__ W1, signed char* __restrict__ W1p, int* __restrict__ b1,
                            const int* __restrict__ W2, signed char* __restrict__ W2p, int* __restrict__ b2) {
  unsigned blk = blockIdx.x;
  if (blk < 4096u) {                 // W0: 4096x1025, 1Mi packed dwords
    pack_body(W0, W0p, b0, blk, 8);
  } else if (blk < 20480u) {         // W1: 4096x4097, 4Mi
    pack_body(W1, W1p, b1, blk - 4096u, 10);
  } else if (blk < 24576u) {         // W2: 1024x4097, 1Mi
    pack_body(W2, W2p, b2, blk - 20480u, 10);
  } else {                           // quant x: 1Mi float4 groups
    unsigned t = (blk - 24576u) * 256u + threadIdx.x;
    float s = QMAX / pAin[0];
    float4 v = reinterpret_cast<const float4*>(x)[t];
    int q0 = (int)fminf(fmaxf(rintf(v.x * s), -QMAX), QMAX);
    int q1 = (int)fminf(fmaxf(rintf(v.y * s), -QMAX), QMAX);
    int q2 = (int)fminf(fmaxf(rintf(v.z * s), -QMAX), QMAX);
    int q3 = (int)fminf(fmaxf(rintf(v.w * s), -QMAX), QMAX);
    unsigned packed = (unsigned)(q0 & 0xff) | ((unsigned)(q1 & 0xff) << 8) |
                      ((unsigned)(q2 & 0xff) << 16) | ((unsigned)(q3 & 0xff) << 24);
    reinterpret_cast<unsigned*>(qa0)[t] = packed;
  }
}

// =====================================================================
// 256x256-tile 8-phase int8 GEMM. 8 waves (2M x 4N), per-wave out 128x64,
// BK=128 B, LDS 128 KiB dbuf. MFMA clusters split by (M-quadrant, k-half):
// each cluster = 16 MFMA needing 4 A-reads + 4 B-reads -> reads spread
// {16,4,4,0} per half-tile with one-phase lookahead; compiler inserts
// counted lgkmcnt per-cluster. Explicit lgkmcnt(0) only where a region's
// reads must drain before the barrier preceding its staging (WAR safety).
// vmcnt(6) at ph4/ph8 only (3 half-tiles = 6 loads stay in flight).
// =====================================================================

#define FENCE() asm volatile("" ::: "memory")
#define BARRIER()                      \
  do {                                 \
    FENCE();                           \
    __builtin_amdgcn_s_barrier();      \
    FENCE();                           \
  } while (0)
#define LGK0() asm volatile("s_waitcnt lgkmcnt(0)" ::: "memory")
#define VMC6() asm volatile("s_waitcnt vmcnt(6)" ::: "memory")
#define VMC0() asm volatile("s_waitcnt vmcnt(0)" ::: "memory")

#define STAGE_A(bf, h, t)                                                     \
  do {                                                                        \
    const signed char* _g = gA + (size_t)((h) * 128) * K + (size_t)(t) * 128; \
    signed char* _l = ldsA + (bf) * 32768 + (h) * 16384 + ldsThr;             \
    gload_lds16(_g, _l);                                                      \
    gload_lds16(_g + (size_t)8 * K, _l + 1024);                               \
  } while (0)

#define STAGE_B(bf, h, t)                                                     \
  do {                                                                        \
    const signed char* _g = gB + (size_t)((h) * 128) * K + (size_t)(t) * 128; \
    signed char* _l = ldsB + (bf) * 32768 + (h) * 16384 + ldsThr;             \
    gload_lds16(_g, _l);                                                      \
    gload_lds16(_g + (size_t)8 * K, _l + 1024);                               \
  } while (0)

// 4 ds_read_b128: A quadrant qm, k-half kk -> dst[0..3]
#define LDAQ(bf, qm, kk, dst)                                                 \
  do {                                                                        \
    _Pragma("unroll") for (int m = 0; m < 4; ++m) {                           \
      int row = wm * 128 + (qm) * 64 + m * 16 + l15;                          \
      int off = ((kk) * 64 + hi * 16) ^ ((row & 7) << 4);                     \
      dst[m] = *(const v4i*)(ldsA + (bf) * 32768 + row * 128 + off);          \
    }                                                                         \
  } while (0)

// 4 ds_read_b128: B all-n, k-half kk -> bR[n][kk]
#define LDBH(bf, kk)                                                          \
  do {                                                                        \
    _Pragma("unroll") for (int n = 0; n < 4; ++n) {                           \
      int row = wn * 64 + n * 16 + l15;                                       \
      int off = ((kk) * 64 + hi * 16) ^ ((row & 7) << 4);                     \
      bR[n][kk] = *(const v4i*)(ldsB + (bf) * 32768 + row * 128 + off);       \
    }                                                                         \
  } while (0)

// 16 MFMA: quadrant qm, k-half kk, A operands in asrc[0..3]
#define MFMAQK(qm, kk, asrc)                                                  \
  do {                                                                        \
    __builtin_amdgcn_s_setprio(1);                                            \
    _Pragma("unroll") for (int m = 0; m < 4; ++m)                             \
    _Pragma("unroll") for (int n = 0; n < 4; ++n)                             \
      acc[(qm) * 4 + m][n] = __builtin_amdgcn_mfma_i32_16x16x64_i8(           \
          asrc[m], bR[n][kk], acc[(qm) * 4 + m][n], 0, 0, 0);                 \
    __builtin_amdgcn_s_setprio(0);                                            \
  } while (0)

__global__ __launch_bounds__(512, 2)
void qgemm256_kernel(const signed char* __restrict__ A,
                     const signed char* __restrict__ Bw,
                     const int* __restrict__ bias,
                     signed char* __restrict__ O,
                     int N, int K, int nbn,
                     const float* __restrict__ pAin,
                     const float* __restrict__ pAw,
                     const float* __restrict__ pAnext) {
  extern __shared__ signed char lds[];
  signed char* ldsA = lds;           // buf0 [0,32K), buf1 [32K,64K)
  signed char* ldsB = lds + 65536;

  const int nwg = gridDim.x, bid = blockIdx.x, per = nwg >> 3;
  const int swz = (bid & 7) * per + (bid >> 3);
  const int brow = swz / nbn, bcol = swz - brow * nbn;
  const int browBase = brow << 8, bcolBase = bcol << 8;

  const int tid = threadIdx.x;
  const int lane = tid & 63, l15 = lane & 15, hi = lane >> 4;
  const int wid = tid >> 6, wm = wid >> 2, wn = wid & 3;

  const int rloc = (wid << 4) + (lane >> 3);
  const int csrc = (lane & 7) ^ ((lane >> 3) & 7);
  const signed char* gA = A + (size_t)(browBase + rloc) * K + csrc * 16;
  const signed char* gB = Bw + (size_t)(bcolBase + rloc) * K + csrc * 16;
  const int ldsThr = (wid << 11) + lane * 16;

  v4i acc[8][4] = {};
  v4i bR[4][2];

  const int nk = K >> 7, niter = nk >> 1, nkm = nk - 1;

  // prologue: t0 {B0,B1,A0,A1}, t1 {B0,B1,A0}; leave 3 half-tiles (6) in flight
  STAGE_B(0, 0, 0); STAGE_B(0, 1, 0); STAGE_A(0, 0, 0); STAGE_A(0, 1, 0);
  STAGE_B(1, 0, 1); STAGE_B(1, 1, 1); STAGE_A(1, 0, 1);
  VMC6();
  BARRIER();

#pragma unroll 1
  for (int i = 0; i < niter; ++i) {
    const int t1 = 2 * i + 1;
    const int tE = (2 * i + 2) & nkm;   // wrapped: always issue (exact vmcnt)
    const int tO = (2 * i + 3) & nkm;
    v4i a00[4], a01[4], a10[4], a11[4];
    // ---- even half (buf0) ----
    // ph1: all B reads + A-q0 reads; stage buf1.A1 (buf1.A drained prev ph7)
    LDAQ(0, 0, 0, a00); LDBH(0, 0); LDAQ(0, 0, 1, a01); LDBH(0, 1);
    STAGE_A(1, 1, t1);
    BARRIER();
    MFMAQK(0, 0, a00);
    LGK0();            // all buf0.B reads drained before B staging begins
    BARRIER();
    // ph2: lookahead A-q1/k0; stage tE.B0 (safe: drained ph1)
    LDAQ(0, 1, 0, a10);
    STAGE_B(0, 0, tE);
    BARRIER();
    MFMAQK(0, 1, a01);
    BARRIER();
    // ph3: lookahead A-q1/k1; stage tE.B1
    LDAQ(0, 1, 1, a11);
    STAGE_B(0, 1, tE);
    BARRIER();
    MFMAQK(1, 0, a10);
    LGK0();            // all buf0.A reads drained before A staging begins
    BARRIER();
    // ph4: stage tE.A0; counted wait -> buf1 fully staged
    STAGE_A(0, 0, tE);
    VMC6();
    BARRIER();
    MFMAQK(1, 1, a11);
    BARRIER();
    // ---- odd half (buf1) ----
    // ph5: stage tE.A1 (buf0.A drained ph3)
    LDAQ(1, 0, 0, a00); LDBH(1, 0); LDAQ(1, 0, 1, a01); LDBH(1, 1);
    STAGE_A(0, 1, tE);
    BARRIER();
    MFMAQK(0, 0, a00);
    LGK0();
    BARRIER();
    // ph6: stage tO.B0
    LDAQ(1, 1, 0, a10);
    STAGE_B(1, 0, tO);
    BARRIER();
    MFMAQK(0, 1, a01);
    BARRIER();
    // ph7: stage tO.B1
    LDAQ(1, 1, 1, a11);
    STAGE_B(1, 1, tO);
    BARRIER();
    MFMAQK(1, 0, a10);
    LGK0();
    BARRIER();
    // ph8: stage tO.A0; counted wait -> buf0 fully staged
    STAGE_A(1, 0, tO);
    VMC6();
    BARRIER();
    MFMAQK(1, 1, a11);
    BARRIER();
  }

  VMC0();  // drain orphan prefetches before LDS dealloc / epilogue

  const float sDeq = (pAw[0] * pAin[0]) / (QMAX * QMAX);
  const float sQ = QMAX / pAnext[0];
#pragma unroll
  for (int nf = 0; nf < 4; ++nf) {
    const int gcol = bcolBase + wn * 64 + nf * 16 + l15;
    const int bv = bias[gcol];
#pragma unroll
    for (int mf = 0; mf < 8; ++mf) {
      const int gr = browBase + wm * 128 + mf * 16 + (hi << 2);
#pragma unroll
      for (int r = 0; r < 4; ++r) {
        float f = (float)(acc[mf][nf][r] + bv) * sDeq;
        f = fmaxf(f, 0.0f);
        float qf = fminf(fmaxf(rintf(f * sQ), -QMAX), QMAX);
        O[(size_t)(gr + r) * N + gcol] = (signed char)(int)qf;
      }
    }
  }
}

// ---------------- 128x128-tile 2-barrier int8 GEMM (layer 2, f32 out) -------
__global__ __launch_bounds__(256)
void qgemm_kernel(const signed char* __restrict__ A,
                  const signed char* __restrict__ Bw,
                  const int* __restrict__ bias,
                  float* __restrict__ O,
                  int N, int K, int nbn,
                  const float* __restrict__ pAin,
                  const float* __restrict__ pAw) {
  __shared__ signed char slds[32768];
  signed char* ldsA = slds;
  signed char* ldsB = slds + 16384;

  int nwg = gridDim.x;
  int bid = blockIdx.x;
  int per = nwg >> 3;
  int swz = (bid & 7) * per + (bid >> 3);
  int brow = swz / nbn;
  int bcol = swz - brow * nbn;
  int browBase = brow << 7;
  int bcolBase = bcol << 7;

  int tid = threadIdx.x;
  int lane = tid & 63;
  int l15 = lane & 15;
  int hi = lane >> 4;
  int wid = tid >> 6;
  int wr = (wid >> 1) << 6;
  int wc = (wid & 1) << 6;

  v4i acc[4][4] = {};

  int nk = K >> 7;
  for (int kt = 0; kt < nk; ++kt) {
    int k0 = kt << 7;
#pragma unroll
    for (int i = 0; i < 4; ++i) {
      int c = i * 256 + tid;
      int r = c >> 3;
      int osrc = ((c & 7) << 4) ^ ((r & 7) << 4);
      gload_lds16(A + (size_t)(browBase + r) * K + (k0 + osrc), ldsA + c * 16);
      gload_lds16(Bw + (size_t)(bcolBase + r) * K + (k0 + osrc), ldsB + c * 16);
    }
    __syncthreads();
#pragma unroll
    for (int kk = 0; kk < 2; ++kk) {
      v4i a[4], b[4];
#pragma unroll
      for (int m = 0; m < 4; ++m) {
        int row = wr + m * 16 + l15;
        int off = (kk * 64 + hi * 16) ^ ((row & 7) << 4);
        a[m] = *reinterpret_cast<const v4i*>(ldsA + row * 128 + off);
      }
#pragma unroll
      for (int n = 0; n < 4; ++n) {
        int row = wc + n * 16 + l15;
        int off = (kk * 64 + hi * 16) ^ ((row & 7) << 4);
        b[n] = *reinterpret_cast<const v4i*>(ldsB + row * 128 + off);
      }
#pragma unroll
      for (int m = 0; m < 4; ++m)
#pragma unroll
        for (int n = 0; n < 4; ++n)
          acc[m][n] = __builtin_amdgcn_mfma_i32_16x16x64_i8(a[m], b[n], acc[m][n], 0, 0, 0);
    }
    __syncthreads();
  }

  float sDeq = (pAw[0] * pAin[0]) / (QMAX * QMAX);
#pragma unroll
  for (int n = 0; n < 4; ++n) {
    int gcol = bcolBase + wc + n * 16 + l15;
    int bv = bias[gcol];
#pragma unroll
    for (int m = 0; m < 4; ++m) {
      int growb = browBase + wr + m * 16 + (hi << 2);
#pragma unroll
      for (int r = 0; r < 4; ++r) {
        O[(size_t)(growb + r) * N + gcol] = (float)(acc[m][n][r] + bv) * sDeq;
      }
    }
  }
}

extern "C" void kernel_launch(void* const* d_in, const int* in_sizes, int n_in,
                              void* d_out, int out_size, void* d_ws, size_t ws_size,
                              hipStream_t stream) {
  const float* x     = (const float*)d_in[0];
  const float* a_in0 = (const float*)d_in[1];
  const float* a_w0  = (const float*)d_in[2];
  const float* a_in2 = (const float*)d_in[3];
  const float* a_w2  = (const float*)d_in[4];
  const float* a_in4 = (const float*)d_in[5];
  const float* a_w4  = (const float*)d_in[6];
  const int*   W0    = (const int*)d_in[7];
  const int*   W1    = (const int*)d_in[8];
  const int*   W2    = (const int*)d_in[9];
  float* out = (float*)d_out;

  constexpr int B = 4096, IN = 1024, H0 = 4096, H1 = 4096, OUTN = 1024;

  char* ws = (char*)d_ws;
  size_t off = 0;
  auto alloc = [&](size_t sz) {
    char* p = ws + off;
    off += (sz + 255) & ~(size_t)255;
    return p;
  };
  signed char* qa0 = (signed char*)alloc((size_t)B * IN);
  signed char* qa1 = (signed char*)alloc((size_t)B * H0);
  signed char* qa2 = (signed char*)alloc((size_t)B * H1);
  signed char* W0p = (signed char*)alloc((size_t)H0 * IN);
  signed char* W1p = (signed char*)alloc((size_t)H1 * H0);
  signed char* W2p = (signed char*)alloc((size_t)OUTN * H1);
  int* b0 = (int*)alloc((size_t)H0 * 4);
  int* b1 = (int*)alloc((size_t)H1 * 4);
  int* b2 = (int*)alloc((size_t)OUTN * 4);

  hipFuncSetAttribute((const void*)qgemm256_kernel,
                      hipFuncAttributeMaxDynamicSharedMemorySize, 131072);

  // merged prep: pack W0/W1/W2 + quantize x (1 launch, 28672 blocks)
  prep_kernel<<<28672, 256, 0, stream>>>(x, qa0, a_in0,
                                         W0, W0p, b0,
                                         W1, W1p, b1,
                                         W2, W2p, b2);

  // layer 0: [B,IN]x[H0,IN]^T -> qa1 (int8), grid 16x16=256
  qgemm256_kernel<<<(B / 256) * (H0 / 256), 512, 131072, stream>>>(
      qa0, W0p, b0, qa1, H0, IN, H0 / 256, a_in0, a_w0, a_in2);

  // layer 1: [B,H0]x[H1,H0]^T -> qa2 (int8), grid 16x16=256
  qgemm256_kernel<<<(B / 256) * (H1 / 256), 512, 131072, stream>>>(
      qa1, W1p, b1, qa2, H1, H0, H1 / 256, a_in2, a_w2, a_in4);

  // layer 2: [B,H1]x[OUT,H1]^T -> f32 out, 128^2 kernel, grid 32x8=256
  qgemm_kernel<<<(B / 128) * (OUTN / 128), 256, 0, stream>>>(
      qa2, W2p, b2, out, OUTN, H1, OUTN / 128, a_in4, a_w4);
}